// Round 2
// baseline (788.278 us; speedup 1.0000x reference)
//
#include <hip/hip_runtime.h>
#include <hip/hip_bf16.h>

// GCN 'attn'-normalized conv (fp32 I/O — reference dtypes):
//   deg_out[i] = #edges dst==i; deg_in[j] = #edges src==j (clamped >=1)
//   w_e = deg_out[row]^-0.5 * deg_in[col]^-0.5
//   agg[row] += w_e * x[col]    (scatter over E=1.6M edges, D=64)
//   out = agg @ W^T + b         (64x64 projection)
//
// Inputs: x fp32[N*64], edge_index int32[2*E] ([2,E] row-major: first E = dst,
// second E = src), W fp32[64*64] ([dout][k]), b fp32[64]. Output fp32[N*64].
// Workspace (fp32): deg_out[N] | deg_in[N] | acc[N*64]  (~26.4 MB)

__global__ void deg_kernel(const int* __restrict__ idx,
                           float* __restrict__ deg_out,
                           float* __restrict__ deg_in, int E) {
    int e = blockIdx.x * blockDim.x + threadIdx.x;
    if (e < E) {
        atomicAdd(&deg_out[idx[e]], 1.0f);      // dst degree
        atomicAdd(&deg_in[idx[E + e]], 1.0f);   // src degree
    }
}

// One wave (64 lanes) per edge; lane d handles feature d.
// x gather: 64 lanes * 4B contiguous = 256B per edge (coalesced).
// atomicAdd: 64 contiguous fp32 addresses (no intra-wave same-address aliasing).
__global__ void scatter_kernel(const int* __restrict__ idx,
                               const float* __restrict__ x,
                               const float* __restrict__ deg_out,
                               const float* __restrict__ deg_in,
                               float* __restrict__ acc, int E) {
    long long t = (long long)blockIdx.x * blockDim.x + threadIdx.x;
    int e = (int)(t >> 6);
    int d = (int)(t & 63);
    if (e >= E) return;
    int row = idx[e];
    int col = idx[E + e];
    float w = rsqrtf(fmaxf(deg_out[row], 1.0f)) *
              rsqrtf(fmaxf(deg_in[col], 1.0f));
    float v = w * x[(long long)col * 64 + d];
    atomicAdd(&acc[(long long)row * 64 + d], v);
}

// out[n][d] = sum_k acc[n][k] * W[d][k] + b[d]
// W staged transposed in LDS: Wt[k*64+d] -> lane d hits bank d%32
// (2 lanes/bank for fp32 = conflict-free on gfx950 per m136).
__global__ void gemm_kernel(const float* __restrict__ acc,
                            const float* __restrict__ W,
                            const float* __restrict__ b,
                            float* __restrict__ out, int N) {
    __shared__ float Wt[64 * 64];
    int tid = threadIdx.x;
    for (int i = tid; i < 64 * 64; i += blockDim.x) {
        int dd = i >> 6;     // dout
        int kk = i & 63;     // k
        Wt[kk * 64 + dd] = W[i];   // W[dd][kk] -> Wt[kk][dd]
    }
    __syncthreads();
    int t = blockIdx.x * blockDim.x + tid;
    int n = t >> 6;
    int d = t & 63;
    if (n >= N) return;
    float sum = b[d];
    const float* __restrict__ a = acc + (long long)n * 64;
#pragma unroll
    for (int k = 0; k < 64; ++k) {
        sum = fmaf(a[k], Wt[k * 64 + d], sum);  // a[k] is wave-uniform (broadcast)
    }
    out[(long long)n * 64 + d] = sum;
}

extern "C" void kernel_launch(void* const* d_in, const int* in_sizes, int n_in,
                              void* d_out, int out_size, void* d_ws, size_t ws_size,
                              hipStream_t stream) {
    const float* x  = (const float*)d_in[0];
    const int*  idx = (const int*)d_in[1];
    const float* W  = (const float*)d_in[2];
    const float* b  = (const float*)d_in[3];
    float*      out = (float*)d_out;

    const int N = in_sizes[0] / 64;
    const int E = in_sizes[1] / 2;

    float* deg_out = (float*)d_ws;
    float* deg_in  = deg_out + N;
    float* acc     = deg_in + N;

    // zero degrees + accumulator (harness poisons ws with 0xAA every call)
    size_t zero_bytes = ((size_t)2 * N + (size_t)N * 64) * sizeof(float);
    hipMemsetAsync(d_ws, 0, zero_bytes, stream);

    deg_kernel<<<(E + 255) / 256, 256, 0, stream>>>(idx, deg_out, deg_in, E);

    long long total = (long long)E * 64;
    scatter_kernel<<<(int)((total + 255) / 256), 256, 0, stream>>>(
        idx, x, deg_out, deg_in, acc, E);

    gemm_kernel<<<(N * 64 + 255) / 256, 256, 0, stream>>>(acc, W, b, out, N);
}

// Round 3
// 581.819 us; speedup vs baseline: 1.3549x; 1.3549x over previous
//
#include <hip/hip_runtime.h>

// GCN 'attn' conv, CSR-on-the-fly formulation (all fp32):
//   deg_dst[i] = #edges dst==i ; deg_src[j] = #edges src==j
//   w_e = max(deg_dst[dst],1)^-0.5 * max(deg_src[src],1)^-0.5
//   y = x @ W^T                      (dense 64x64 projection, done FIRST --
//                                     linearity: A_hat@(xW^T) = (A_hat@x)W^T)
//   out[n] = sum_{e: dst==n} w_e * y[src_e] + b    (gather-side SpMM, no atomics)
//
// CSR built per call without sorting: base[n] allocated via wave-scan + one
// cursor atomic per wave (bucket ORDER is irrelevant, only contiguity).
//
// ws layout (4B units): deg_dst[N] | deg_src[N] | off[N] | cursor(+63 pad) |
//                       base[N] | (align 256B) y[N*64] | pairs{col,w}[E]
// ~40 MB total. Only the first (3N+64)*4 bytes need zeroing.

struct __align__(8) Edge { int col; float w; };

__global__ void deg_kernel(const int* __restrict__ idx,
                           int* __restrict__ deg_dst,
                           int* __restrict__ deg_src, int E) {
    int e = blockIdx.x * blockDim.x + threadIdx.x;
    if (e < E) {
        atomicAdd(&deg_dst[idx[e]], 1);       // dst degree
        atomicAdd(&deg_src[idx[E + e]], 1);   // src degree
    }
}

// One thread per node; each wave scans its 64 nodes' degrees and grabs a
// contiguous chunk of the edge pool with ONE cursor atomic per wave.
__global__ void alloc_kernel(const int* __restrict__ deg_dst,
                             int* __restrict__ base,
                             int* __restrict__ cursor, int N) {
    int n = blockIdx.x * blockDim.x + threadIdx.x;
    int lane = threadIdx.x & 63;
    int d = (n < N) ? deg_dst[n] : 0;
    int incl = d;
#pragma unroll
    for (int off = 1; off < 64; off <<= 1) {
        int v = __shfl_up(incl, off, 64);
        if (lane >= off) incl += v;
    }
    int excl = incl - d;
    int total = __shfl(incl, 63, 64);
    int wbase = 0;
    if (lane == 63) wbase = atomicAdd(cursor, total);
    wbase = __shfl(wbase, 63, 64);
    if (n < N) base[n] = wbase + excl;
}

// Scatter each edge's {src, w} into its dst bucket (int atomic for slot).
__global__ void fill_kernel(const int* __restrict__ idx,
                            const int* __restrict__ deg_dst,
                            const int* __restrict__ deg_src,
                            const int* __restrict__ base,
                            int* __restrict__ off,
                            Edge* __restrict__ pairs, int E) {
    int e = blockIdx.x * blockDim.x + threadIdx.x;
    if (e >= E) return;
    int dst = idx[e];
    int src = idx[E + e];
    float w = rsqrtf(fmaxf((float)deg_dst[dst], 1.0f)) *
              rsqrtf(fmaxf((float)deg_src[src], 1.0f));
    int pos = base[dst] + atomicAdd(&off[dst], 1);
    Edge ed; ed.col = src; ed.w = w;
    pairs[pos] = ed;   // single 8B store
}

// y[n][d] = sum_k x[n][k] * W[d][k]   (W transposed in LDS; lane d -> bank
// d%32, 2 lanes/bank = conflict-free; x[n][k] wave-uniform broadcast)
__global__ void proj_kernel(const float* __restrict__ x,
                            const float* __restrict__ W,
                            float* __restrict__ y, int N) {
    __shared__ float Wt[64 * 64];
    int tid = threadIdx.x;
    for (int i = tid; i < 64 * 64; i += blockDim.x)
        Wt[(i & 63) * 64 + (i >> 6)] = W[i];   // W[d][k] -> Wt[k][d]
    __syncthreads();
    int t = blockIdx.x * blockDim.x + tid;
    int n = t >> 6;
    int d = t & 63;
    if (n >= N) return;
    const float* __restrict__ a = x + (long long)n * 64;
    float sum = 0.0f;
#pragma unroll
    for (int k = 0; k < 64; ++k)
        sum = fmaf(a[k], Wt[k * 64 + d], sum);
    y[(long long)n * 64 + d] = sum;
}

// One wave per dst node; lane d accumulates feature d in a register.
// Per edge: one broadcast 8B pair load + one coalesced 256B row load. No atomics.
__global__ void spmm_kernel(const Edge* __restrict__ pairs,
                            const int* __restrict__ base,
                            const int* __restrict__ deg_dst,
                            const float* __restrict__ y,
                            const float* __restrict__ b,
                            float* __restrict__ out, int N) {
    long long t = (long long)blockIdx.x * blockDim.x + threadIdx.x;
    int n = (int)(t >> 6);
    int lane = (int)(t & 63);
    if (n >= N) return;
    int s = base[n];
    int cnt = deg_dst[n];
    const Edge* __restrict__ p = pairs + s;
    float acc = 0.0f;
    int i = 0;
    for (; i + 2 <= cnt; i += 2) {         // unroll 2 -> 2 gathers in flight
        Edge e0 = p[i];
        Edge e1 = p[i + 1];
        float v0 = y[(long long)e0.col * 64 + lane];
        float v1 = y[(long long)e1.col * 64 + lane];
        acc = fmaf(e0.w, v0, acc);
        acc = fmaf(e1.w, v1, acc);
    }
    if (i < cnt) {
        Edge e0 = p[i];
        acc = fmaf(e0.w, y[(long long)e0.col * 64 + lane], acc);
    }
    out[(long long)n * 64 + lane] = acc + b[lane];
}

extern "C" void kernel_launch(void* const* d_in, const int* in_sizes, int n_in,
                              void* d_out, int out_size, void* d_ws, size_t ws_size,
                              hipStream_t stream) {
    const float* x  = (const float*)d_in[0];
    const int*  idx = (const int*)d_in[1];
    const float* W  = (const float*)d_in[2];
    const float* b  = (const float*)d_in[3];
    float*      out = (float*)d_out;

    const int N = in_sizes[0] / 64;
    const int E = in_sizes[1] / 2;

    int* deg_dst = (int*)d_ws;
    int* deg_src = deg_dst + N;
    int* off     = deg_src + N;
    int* cursor  = off + N;          // 1 int used, 64 reserved
    int* base    = cursor + 64;
    size_t yoff  = ((size_t)(4 * (size_t)N + 128) + 63) & ~(size_t)63;  // 256B align
    float* y     = (float*)d_ws + yoff;
    Edge* pairs  = (Edge*)(y + (size_t)N * 64);

    // zero deg_dst, deg_src, off, cursor (harness poisons ws with 0xAA)
    hipMemsetAsync(d_ws, 0, (size_t)(3 * (size_t)N + 64) * sizeof(int), stream);

    deg_kernel<<<(E + 255) / 256, 256, 0, stream>>>(idx, deg_dst, deg_src, E);

    alloc_kernel<<<(N + 255) / 256, 256, 0, stream>>>(deg_dst, base, cursor, N);

    fill_kernel<<<(E + 255) / 256, 256, 0, stream>>>(idx, deg_dst, deg_src,
                                                     base, off, pairs, E);

    proj_kernel<<<(N * 64 + 255) / 256, 256, 0, stream>>>(x, W, y, N);

    spmm_kernel<<<(N * 64 + 255) / 256, 256, 0, stream>>>(pairs, base, deg_dst,
                                                          y, b, out, N);
}

// Round 4
// 365.238 us; speedup vs baseline: 2.1583x; 1.5930x over previous
//
#include <hip/hip_runtime.h>
#include <hip/hip_bf16.h>

// GCN 'attn' conv, CSR-on-the-fly (fp32 in/out, bf16 intermediate y):
//   deg_dst[i] = #edges dst==i ; deg_src[j] = #edges src==j
//   w_e = max(deg_dst,1)^-0.5 * max(deg_src,1)^-0.5
//   y = bf16( x @ W^T )            (projection FIRST; linearity)
//   out[n] = sum_{e: dst==n} w_e * y[src_e] + b    (gather SpMM, no atomics)
//
// ws (4B units): deg_dst[N] | deg_src[N] | off[N] | cursor(+63) | base[N] |
//                (256B align) y_bf16[N*64] | pairs{col,w}[E]   (~27 MB)

struct __align__(8) Edge { int col; float w; };

__device__ __forceinline__ unsigned short bfbits(float f) {
    __hip_bfloat16 h = __float2bfloat16(f);
    return *reinterpret_cast<unsigned short*>(&h);
}

__global__ void deg_kernel(const int* __restrict__ idx,
                           int* __restrict__ deg_dst,
                           int* __restrict__ deg_src, int E) {
    int e = blockIdx.x * blockDim.x + threadIdx.x;
    if (e < E) {
        atomicAdd(&deg_dst[idx[e]], 1);
        atomicAdd(&deg_src[idx[E + e]], 1);
    }
}

// Wave-scan allocation of contiguous CSR buckets (order irrelevant).
__global__ void alloc_kernel(const int* __restrict__ deg_dst,
                             int* __restrict__ base,
                             int* __restrict__ cursor, int N) {
    int n = blockIdx.x * blockDim.x + threadIdx.x;
    int lane = threadIdx.x & 63;
    int d = (n < N) ? deg_dst[n] : 0;
    int incl = d;
#pragma unroll
    for (int off = 1; off < 64; off <<= 1) {
        int v = __shfl_up(incl, off, 64);
        if (lane >= off) incl += v;
    }
    int excl = incl - d;
    int total = __shfl(incl, 63, 64);
    int wbase = 0;
    if (lane == 63) wbase = atomicAdd(cursor, total);
    wbase = __shfl(wbase, 63, 64);
    if (n < N) base[n] = wbase + excl;
}

__global__ void fill_kernel(const int* __restrict__ idx,
                            const int* __restrict__ deg_dst,
                            const int* __restrict__ deg_src,
                            const int* __restrict__ base,
                            int* __restrict__ off,
                            Edge* __restrict__ pairs, int E) {
    int e = blockIdx.x * blockDim.x + threadIdx.x;
    if (e >= E) return;
    int dst = idx[e];
    int src = idx[E + e];
    float w = rsqrtf(fmaxf((float)deg_dst[dst], 1.0f)) *
              rsqrtf(fmaxf((float)deg_src[src], 1.0f));
    int pos = base[dst] + atomicAdd(&off[dst], 1);
    Edge ed; ed.col = src; ed.w = w;
    pairs[pos] = ed;
}

// y[n][d] = bf16( sum_k x[n][k] * W[d][k] )
// Wave = 4 nodes (nl=lane>>4); lane g=lane&15 owns outputs d=4g..4g+3.
// Wt LDS stride 68 dwords: staging writes 8-way (16 wave-writes/block,
// amortized over ~64 nodes via grid-stride); b128 reads 2-way + 4-node
// broadcast = conflict-free; b128 16B-aligned (68%4==0).
__global__ void proj_kernel(const float* __restrict__ x,
                            const float* __restrict__ W,
                            __hip_bfloat16* __restrict__ y, int N) {
    __shared__ float Wt[64 * 68];
    int tid = threadIdx.x;
    for (int i = tid; i < 4096; i += 256) {
        int k = i & 63, dd = i >> 6;
        Wt[k * 68 + dd] = W[dd * 64 + k];   // coalesced global read
    }
    __syncthreads();

    int lane = tid & 63;
    int nl = lane >> 4;      // node within quad
    int g  = lane & 15;      // output quad: d = 4g..4g+3
    int wid = (blockIdx.x * blockDim.x + tid) >> 6;
    int nwaves = (gridDim.x * blockDim.x) >> 6;
    int ngrp = (N + 3) >> 2;

    for (int grp = wid; grp < ngrp; grp += nwaves) {
        int n = grp * 4 + nl;
        if (n >= N) continue;
        const float4* __restrict__ xr = (const float4*)(x + (long long)n * 64);
        float a0 = 0.f, a1 = 0.f, a2 = 0.f, a3 = 0.f;
#pragma unroll
        for (int kc = 0; kc < 16; ++kc) {
            float4 xv = xr[kc];
            const float* wp = &Wt[(kc * 4) * 68 + 4 * g];
            float4 w0 = *(const float4*)(wp);
            float4 w1 = *(const float4*)(wp + 68);
            float4 w2 = *(const float4*)(wp + 136);
            float4 w3 = *(const float4*)(wp + 204);
            a0 = fmaf(xv.x, w0.x, a0); a1 = fmaf(xv.x, w0.y, a1);
            a2 = fmaf(xv.x, w0.z, a2); a3 = fmaf(xv.x, w0.w, a3);
            a0 = fmaf(xv.y, w1.x, a0); a1 = fmaf(xv.y, w1.y, a1);
            a2 = fmaf(xv.y, w1.z, a2); a3 = fmaf(xv.y, w1.w, a3);
            a0 = fmaf(xv.z, w2.x, a0); a1 = fmaf(xv.z, w2.y, a1);
            a2 = fmaf(xv.z, w2.z, a2); a3 = fmaf(xv.z, w2.w, a3);
            a0 = fmaf(xv.w, w3.x, a0); a1 = fmaf(xv.w, w3.y, a1);
            a2 = fmaf(xv.w, w3.z, a2); a3 = fmaf(xv.w, w3.w, a3);
        }
        ushort4 pk;
        pk.x = bfbits(a0); pk.y = bfbits(a1);
        pk.z = bfbits(a2); pk.w = bfbits(a3);
        *(ushort4*)((unsigned short*)y + (long long)n * 64 + 4 * g) = pk;
    }
}

// One wave per dst node. lane = eg*8 + h: edge-group eg=0..7, feature chunk h
// (16B = 8 bf16). One dwordx4/lane gathers 8 y-rows per wave-instr; unroll x2
// -> 16 edges in flight. fp32 acc, shfl_xor reduce over groups, float4 stores.
__global__ void spmm_kernel(const Edge* __restrict__ pairs,
                            const int* __restrict__ base,
                            const int* __restrict__ deg_dst,
                            const unsigned short* __restrict__ y,
                            const float* __restrict__ b,
                            float* __restrict__ out, int N) {
    long long t = (long long)blockIdx.x * blockDim.x + threadIdx.x;
    int n = (int)(t >> 6);
    if (n >= N) return;
    int lane = (int)(t & 63);
    int eg = lane >> 3;      // edge group 0..7
    int h  = lane & 7;       // 16B feature chunk

    int s = base[n];
    int cnt = deg_dst[n];
    const Edge* __restrict__ p = pairs + s;

    float acc[8];
#pragma unroll
    for (int j = 0; j < 8; ++j) acc[j] = 0.f;

    for (int i = 0; i < cnt; i += 16) {
        int e0 = i + eg, e1 = i + 8 + eg;
        Edge p0 = (e0 < cnt) ? p[e0] : Edge{0, 0.f};
        Edge p1 = (e1 < cnt) ? p[e1] : Edge{0, 0.f};
        uint4 r0 = ((const uint4*)(y + (long long)p0.col * 64))[h];
        uint4 r1 = ((const uint4*)(y + (long long)p1.col * 64))[h];
#pragma unroll
        for (int q = 0; q < 2; ++q) {
            uint4 r = q ? r1 : r0;
            float w = q ? p1.w : p0.w;
            unsigned int ws[4] = {r.x, r.y, r.z, r.w};
#pragma unroll
            for (int c = 0; c < 4; ++c) {
                float lo = __uint_as_float(ws[c] << 16);
                float hi = __uint_as_float(ws[c] & 0xffff0000u);
                acc[2 * c]     = fmaf(w, lo, acc[2 * c]);
                acc[2 * c + 1] = fmaf(w, hi, acc[2 * c + 1]);
            }
        }
    }
    // reduce over the 8 edge groups
#pragma unroll
    for (int m = 8; m < 64; m <<= 1)
#pragma unroll
        for (int j = 0; j < 8; ++j) acc[j] += __shfl_xor(acc[j], m, 64);

    if (eg == 0) {
        float4 b0 = ((const float4*)b)[h * 2];
        float4 b1 = ((const float4*)b)[h * 2 + 1];
        float4 o0 = {acc[0] + b0.x, acc[1] + b0.y, acc[2] + b0.z, acc[3] + b0.w};
        float4 o1 = {acc[4] + b1.x, acc[5] + b1.y, acc[6] + b1.z, acc[7] + b1.w};
        float4* op = (float4*)(out + (long long)n * 64);
        op[h * 2] = o0;
        op[h * 2 + 1] = o1;
    }
}

extern "C" void kernel_launch(void* const* d_in, const int* in_sizes, int n_in,
                              void* d_out, int out_size, void* d_ws, size_t ws_size,
                              hipStream_t stream) {
    const float* x  = (const float*)d_in[0];
    const int*  idx = (const int*)d_in[1];
    const float* W  = (const float*)d_in[2];
    const float* b  = (const float*)d_in[3];
    float*      out = (float*)d_out;

    const int N = in_sizes[0] / 64;
    const int E = in_sizes[1] / 2;

    int* deg_dst = (int*)d_ws;
    int* deg_src = deg_dst + N;
    int* off     = deg_src + N;
    int* cursor  = off + N;          // 1 used, 64 reserved
    int* base    = cursor + 64;

    size_t ybyte = (((size_t)(4 * (size_t)N + 64) * 4) + 255) & ~(size_t)255;
    unsigned short* y = (unsigned short*)((char*)d_ws + ybyte);
    Edge* pairs = (Edge*)(y + (size_t)N * 64);

    hipMemsetAsync(d_ws, 0, (size_t)(3 * (size_t)N + 64) * sizeof(int), stream);

    deg_kernel<<<(E + 255) / 256, 256, 0, stream>>>(idx, deg_dst, deg_src, E);

    alloc_kernel<<<(N + 255) / 256, 256, 0, stream>>>(deg_dst, base, cursor, N);

    fill_kernel<<<(E + 255) / 256, 256, 0, stream>>>(idx, deg_dst, deg_src,
                                                     base, off, pairs, E);

    proj_kernel<<<1600, 256, 0, stream>>>(x, W, (__hip_bfloat16*)y, N);

    spmm_kernel<<<(N * 64 + 255) / 256, 256, 0, stream>>>(pairs, base, deg_dst,
                                                          y, b, out, N);
}

// Round 5
// 251.864 us; speedup vs baseline: 3.1298x; 1.4501x over previous
//
#include <hip/hip_runtime.h>
#include <hip/hip_bf16.h>

// GCN 'attn' conv, bucketized build (no random global atomics):
//   out[n] = rsqrt(max(deg_dst[n],1)) * sum_{e: dst==n} y'[src_e] + b
//   y'[j]  = bf16( (x[j] @ W^T) * rsqrt(max(deg_src[j],1)) )
// Sector-traffic model (R4 counters): random device-scope atomics cost a 32B
// sector each (~0.87 TB/s) -> deg/fill were 124/~70 us. This build uses LDS
// histograms per 256-node bucket + chunk-reserved scatter: the only global
// atomics are ~94k chunk reservations.
//
// ws (ints): partial[120][2NB] | bbD[NB+1] | bbS[NB+1] | cursor[2NB] |
//            row_ptr[N+1] | srcfac[N] | entry_pool[E] | key_pool[E] | csr[E] |
//            y_bf16[N*64]   (~33 MB). Every word written before read: no memset.

#define NBLK 120   // blocks for hist/scatter
#define MAXB 512   // max buckets per stream (supports N <= 131072)

// K1: per-block partial histograms over dst-buckets [0,NB) and src-buckets [NB,2NB)
__global__ void hist_kernel(const int* __restrict__ idx, int E, int NB,
                            int* __restrict__ partial) {
    __shared__ int h[2 * MAXB];
    int tid = threadIdx.x;
    for (int i = tid; i < 2 * NB; i += blockDim.x) h[i] = 0;
    __syncthreads();
    int stride = gridDim.x * blockDim.x;
    for (int e = blockIdx.x * blockDim.x + tid; e < E; e += stride) {
        atomicAdd(&h[idx[e] >> 8], 1);            // dst bucket (LDS)
        atomicAdd(&h[NB + (idx[E + e] >> 8)], 1); // src bucket (LDS)
    }
    __syncthreads();
    int* row = partial + (size_t)blockIdx.x * 2 * NB;
    for (int i = tid; i < 2 * NB; i += blockDim.x) row[i] = h[i];
}

// K2: column-sum partials, prefix-sum each stream -> bucket bases + cursors.
__global__ void scan_kernel(const int* __restrict__ partial, int nblk, int NB,
                            int E, int N,
                            int* __restrict__ bbD, int* __restrict__ bbS,
                            int* __restrict__ cursor, int* __restrict__ row_ptr) {
    __shared__ int sc[MAXB];
    int tid = threadIdx.x;  // blockDim = MAXB = 512
    int sumD = 0, sumS = 0;
    if (tid < NB) {
        for (int b = 0; b < nblk; ++b) {
            const int* row = partial + (size_t)b * 2 * NB;
            sumD += row[tid];
            sumS += row[NB + tid];
        }
    }
    // inclusive scan of sumD
    sc[tid] = (tid < NB) ? sumD : 0;
    __syncthreads();
    for (int off = 1; off < MAXB; off <<= 1) {
        int v = (tid >= off) ? sc[tid - off] : 0;
        __syncthreads();
        sc[tid] += v;
        __syncthreads();
    }
    if (tid < NB) { bbD[tid] = sc[tid] - sumD; cursor[tid] = sc[tid] - sumD; }
    if (tid == 0) { bbD[NB] = E; row_ptr[N] = E; }
    __syncthreads();
    // inclusive scan of sumS
    sc[tid] = (tid < NB) ? sumS : 0;
    __syncthreads();
    for (int off = 1; off < MAXB; off <<= 1) {
        int v = (tid >= off) ? sc[tid - off] : 0;
        __syncthreads();
        sc[tid] += v;
        __syncthreads();
    }
    if (tid < NB) { bbS[tid] = sc[tid] - sumS; cursor[NB + tid] = sc[tid] - sumS; }
    if (tid == 0) bbS[NB] = E;
}

// K3: two-pass scatter. Pass A: LDS count. Reserve chunks (one global atomic
// per (block,bucket)). Pass B: LDS-slotted writes of packed entries + src keys.
__global__ void scatter_kernel(const int* __restrict__ idx, int E, int NB,
                               int* __restrict__ cursor,
                               int* __restrict__ entry_pool,
                               int* __restrict__ key_pool) {
    __shared__ int h[2 * MAXB];
    __shared__ int cbase[2 * MAXB];
    int tid = threadIdx.x;
    for (int i = tid; i < 2 * NB; i += blockDim.x) h[i] = 0;
    __syncthreads();
    int stride = gridDim.x * blockDim.x;
    for (int e = blockIdx.x * blockDim.x + tid; e < E; e += stride) {
        atomicAdd(&h[idx[e] >> 8], 1);
        atomicAdd(&h[NB + (idx[E + e] >> 8)], 1);
    }
    __syncthreads();
    for (int i = tid; i < 2 * NB; i += blockDim.x) {
        int c = h[i];
        cbase[i] = (c > 0) ? atomicAdd(&cursor[i], c) : 0;
    }
    __syncthreads();
    for (int i = tid; i < 2 * NB; i += blockDim.x) h[i] = 0;  // reuse as offsets
    __syncthreads();
    for (int e = blockIdx.x * blockDim.x + tid; e < E; e += stride) {
        int dst = idx[e], src = idx[E + e];
        int qd = dst >> 8;
        int sl = atomicAdd(&h[qd], 1);
        entry_pool[cbase[qd] + sl] = (src << 8) | (dst & 255);  // src<2^17 fits
        int qs = NB + (src >> 8);
        int sl2 = atomicAdd(&h[qs], 1);
        key_pool[cbase[qs] + sl2] = src;
    }
}

// K4: per src-bucket count -> srcfac[n] = rsqrt(max(deg_src,1))
__global__ void srccount_kernel(const int* __restrict__ key_pool,
                                const int* __restrict__ bbS,
                                float* __restrict__ srcfac, int N) {
    __shared__ int cnt[256];
    int q = blockIdx.x, tid = threadIdx.x;  // 256 threads
    cnt[tid] = 0;
    __syncthreads();
    int s0 = bbS[q], s1 = bbS[q + 1];
    for (int j = s0 + tid; j < s1; j += 256)
        atomicAdd(&cnt[key_pool[j] & 255], 1);
    __syncthreads();
    int node = q * 256 + tid;
    if (node < N) srcfac[node] = rsqrtf(fmaxf((float)cnt[tid], 1.0f));
}

// K5: per dst-bucket: count, prefix -> row_ptr; place src into CSR slots.
__global__ void order_kernel(const int* __restrict__ entry_pool,
                             const int* __restrict__ bbD,
                             int* __restrict__ row_ptr,
                             int* __restrict__ csr, int N) {
    __shared__ int cnt[256];
    __shared__ int pref[256];
    __shared__ int lcur[256];
    int q = blockIdx.x, tid = threadIdx.x;  // 256 threads
    cnt[tid] = 0;
    __syncthreads();
    int s0 = bbD[q], s1 = bbD[q + 1];
    for (int j = s0 + tid; j < s1; j += 256)
        atomicAdd(&cnt[entry_pool[j] & 255], 1);
    __syncthreads();
    int v = cnt[tid];
    pref[tid] = v;
    __syncthreads();
    for (int off = 1; off < 256; off <<= 1) {     // inclusive scan
        int u = (tid >= off) ? pref[tid - off] : 0;
        __syncthreads();
        pref[tid] += u;
        __syncthreads();
    }
    int excl = pref[tid] - v;
    int node = q * 256 + tid;
    if (node < N) row_ptr[node] = s0 + excl;
    lcur[tid] = 0;
    __syncthreads();
    pref[tid] = excl;
    __syncthreads();
    for (int j = s0 + tid; j < s1; j += 256) {
        int ent = entry_pool[j];
        int dl = ent & 255;
        int sl = atomicAdd(&lcur[dl], 1);
        csr[s0 + pref[dl] + sl] = ent >> 8;   // writes stay in 16KB L2-local region
    }
}

__device__ __forceinline__ unsigned short bfbits(float f) {
    __hip_bfloat16 h = __float2bfloat16(f);
    return *reinterpret_cast<unsigned short*>(&h);
}

// y'[n][d] = bf16( srcfac[n] * sum_k x[n][k] * W[d][k] )
// Wave = 4 nodes; lane g=lane&15 owns outputs 4g..4g+3. Wt stride 68: staging
// 8-way (amortized), b128 reads conflict-free (R4-verified structure).
__global__ void proj_kernel(const float* __restrict__ x,
                            const float* __restrict__ W,
                            const float* __restrict__ srcfac,
                            unsigned short* __restrict__ y, int N) {
    __shared__ float Wt[64 * 68];
    int tid = threadIdx.x;
    for (int i = tid; i < 4096; i += 256) {
        int k = i & 63, dd = i >> 6;
        Wt[k * 68 + dd] = W[dd * 64 + k];
    }
    __syncthreads();

    int lane = tid & 63;
    int nl = lane >> 4;
    int g  = lane & 15;
    int wid = (blockIdx.x * blockDim.x + tid) >> 6;
    int nwaves = (gridDim.x * blockDim.x) >> 6;
    int ngrp = (N + 3) >> 2;

    for (int grp = wid; grp < ngrp; grp += nwaves) {
        int n = grp * 4 + nl;
        if (n >= N) continue;
        const float4* __restrict__ xr = (const float4*)(x + (long long)n * 64);
        float s = srcfac[n];
        float a0 = 0.f, a1 = 0.f, a2 = 0.f, a3 = 0.f;
#pragma unroll
        for (int kc = 0; kc < 16; ++kc) {
            float4 xv = xr[kc];
            const float* wp = &Wt[(kc * 4) * 68 + 4 * g];
            float4 w0 = *(const float4*)(wp);
            float4 w1 = *(const float4*)(wp + 68);
            float4 w2 = *(const float4*)(wp + 136);
            float4 w3 = *(const float4*)(wp + 204);
            a0 = fmaf(xv.x, w0.x, a0); a1 = fmaf(xv.x, w0.y, a1);
            a2 = fmaf(xv.x, w0.z, a2); a3 = fmaf(xv.x, w0.w, a3);
            a0 = fmaf(xv.y, w1.x, a0); a1 = fmaf(xv.y, w1.y, a1);
            a2 = fmaf(xv.y, w1.z, a2); a3 = fmaf(xv.y, w1.w, a3);
            a0 = fmaf(xv.z, w2.x, a0); a1 = fmaf(xv.z, w2.y, a1);
            a2 = fmaf(xv.z, w2.z, a2); a3 = fmaf(xv.z, w2.w, a3);
            a0 = fmaf(xv.w, w3.x, a0); a1 = fmaf(xv.w, w3.y, a1);
            a2 = fmaf(xv.w, w3.z, a2); a3 = fmaf(xv.w, w3.w, a3);
        }
        ushort4 pk;
        pk.x = bfbits(a0 * s); pk.y = bfbits(a1 * s);
        pk.z = bfbits(a2 * s); pk.w = bfbits(a3 * s);
        *(ushort4*)(y + (long long)n * 64 + 4 * g) = pk;
    }
}

// Wave per dst node: unweighted bf16 row sums, final rsqrt(deg) scale + bias.
// lane = eg*8+h: 8 edges/wave-instr via dwordx4, unroll x2 (R4-verified).
__global__ void spmm_kernel(const int* __restrict__ csr,
                            const int* __restrict__ row_ptr,
                            const unsigned short* __restrict__ y,
                            const float* __restrict__ b,
                            float* __restrict__ out, int N) {
    long long t = (long long)blockIdx.x * blockDim.x + threadIdx.x;
    int n = (int)(t >> 6);
    if (n >= N) return;
    int lane = (int)(t & 63);
    int eg = lane >> 3;
    int h  = lane & 7;

    int s0 = row_ptr[n];
    int cnt = row_ptr[n + 1] - s0;

    float acc[8];
#pragma unroll
    for (int j = 0; j < 8; ++j) acc[j] = 0.f;

    for (int i = 0; i < cnt; i += 16) {
        int e0 = i + eg, e1 = i + 8 + eg;
        float m0 = (e0 < cnt) ? 1.f : 0.f;
        float m1 = (e1 < cnt) ? 1.f : 0.f;
        int c0 = (e0 < cnt) ? csr[s0 + e0] : 0;
        int c1 = (e1 < cnt) ? csr[s0 + e1] : 0;
        uint4 r0 = ((const uint4*)(y + (long long)c0 * 64))[h];
        uint4 r1 = ((const uint4*)(y + (long long)c1 * 64))[h];
#pragma unroll
        for (int q = 0; q < 2; ++q) {
            uint4 r = q ? r1 : r0;
            float m = q ? m1 : m0;
            unsigned int ws4[4] = {r.x, r.y, r.z, r.w};
#pragma unroll
            for (int c = 0; c < 4; ++c) {
                float lo = __uint_as_float(ws4[c] << 16);
                float hi = __uint_as_float(ws4[c] & 0xffff0000u);
                acc[2 * c]     = fmaf(m, lo, acc[2 * c]);
                acc[2 * c + 1] = fmaf(m, hi, acc[2 * c + 1]);
            }
        }
    }
#pragma unroll
    for (int m = 8; m < 64; m <<= 1)
#pragma unroll
        for (int j = 0; j < 8; ++j) acc[j] += __shfl_xor(acc[j], m, 64);

    if (eg == 0) {
        float scl = rsqrtf(fmaxf((float)cnt, 1.0f));
        float4 b0 = ((const float4*)b)[h * 2];
        float4 b1 = ((const float4*)b)[h * 2 + 1];
        float4 o0 = {acc[0] * scl + b0.x, acc[1] * scl + b0.y,
                     acc[2] * scl + b0.z, acc[3] * scl + b0.w};
        float4 o1 = {acc[4] * scl + b1.x, acc[5] * scl + b1.y,
                     acc[6] * scl + b1.z, acc[7] * scl + b1.w};
        float4* op = (float4*)(out + (long long)n * 64);
        op[h * 2] = o0;
        op[h * 2 + 1] = o1;
    }
}

extern "C" void kernel_launch(void* const* d_in, const int* in_sizes, int n_in,
                              void* d_out, int out_size, void* d_ws, size_t ws_size,
                              hipStream_t stream) {
    const float* x  = (const float*)d_in[0];
    const int*  idx = (const int*)d_in[1];
    const float* W  = (const float*)d_in[2];
    const float* b  = (const float*)d_in[3];
    float*      out = (float*)d_out;

    const int N = in_sizes[0] / 64;
    const int E = in_sizes[1] / 2;
    const int NB = (N + 255) >> 8;   // 256-node buckets (NB<=MAXB for N<=131072)

    int* ws = (int*)d_ws;
    size_t o = 0;
    int* partial    = ws + o; o += (size_t)NBLK * 2 * NB;
    int* bbD        = ws + o; o += NB + 1;
    int* bbS        = ws + o; o += NB + 1;
    int* cursor     = ws + o; o += 2 * NB;
    int* row_ptr    = ws + o; o += N + 1;
    float* srcfac   = (float*)(ws + o); o += N;
    int* entry_pool = ws + o; o += E;
    int* key_pool   = ws + o; o += E;
    int* csr        = ws + o; o += E;
    o = (o + 63) & ~(size_t)63;
    unsigned short* y = (unsigned short*)(ws + o);

    hist_kernel<<<NBLK, 256, 0, stream>>>(idx, E, NB, partial);

    scan_kernel<<<1, MAXB, 0, stream>>>(partial, NBLK, NB, E, N,
                                        bbD, bbS, cursor, row_ptr);

    scatter_kernel<<<NBLK, 256, 0, stream>>>(idx, E, NB, cursor,
                                             entry_pool, key_pool);

    srccount_kernel<<<NB, 256, 0, stream>>>(key_pool, bbS, srcfac, N);

    order_kernel<<<NB, 256, 0, stream>>>(entry_pool, bbD, row_ptr, csr, N);

    proj_kernel<<<1600, 256, 0, stream>>>(x, W, srcfac, y, N);

    spmm_kernel<<<(N * 64 + 255) / 256, 256, 0, stream>>>(csr, row_ptr, y, b,
                                                          out, N);
}

// Round 6
// 248.499 us; speedup vs baseline: 3.1722x; 1.0135x over previous
//
#include <hip/hip_runtime.h>
#include <hip/hip_bf16.h>

// GCN 'attn' conv, bucketized CSR build with DETERMINISTIC offsets:
//   out[n] = rsqrt(max(deg_dst[n],1)) * sum_{e: dst==n} y'[src_e] + b
//   y'[j]  = bf16( (x[j] @ W^T) * rsqrt(max(deg_src[j],1)) )
// R5 lesson: scatter at NBLK=120 was latency-starved (Occupancy 4.5%, VALU
// 1.6%) -- the chunk-reservation atomic forced small NBLK. Fix: hist's
// per-(block,bucket) counts + a column prefix give EXACT per-block write
// bases -> zero global atomics -> NBLK=512 (2 blocks/CU).
//
// ws (ints): partial[2NB][NBLK] (bucket-major) | totals[2NB] | bbD[NB+1] |
//   bbS[NB+1] | row_ptr[N+1] | srcfac[N] | entry_pool[E] | key_pool[E]
//   (csr ALIASES key_pool: dead after srccount) | y_bf16[N*64]  (~29 MB)
// Every word written before read: no memset needed.

#define NBLK 512   // hist/scatter blocks: 2 per CU
#define MAXB 512   // max 256-node buckets per stream (N <= 131072)

// K1: per-block LDS histograms; bucket-major partial (coalesced colprefix walk)
__global__ void hist_kernel(const int* __restrict__ idx, int E, int NB,
                            int* __restrict__ partial) {
    __shared__ int h[2 * MAXB];
    int tid = threadIdx.x;
    for (int i = tid; i < 2 * NB; i += blockDim.x) h[i] = 0;
    __syncthreads();
    int stride = gridDim.x * blockDim.x;
    for (int e = blockIdx.x * blockDim.x + tid; e < E; e += stride) {
        atomicAdd(&h[idx[e] >> 8], 1);            // dst bucket (LDS)
        atomicAdd(&h[NB + (idx[E + e] >> 8)], 1); // src bucket (LDS)
    }
    __syncthreads();
    for (int i = tid; i < 2 * NB; i += blockDim.x)
        partial[(size_t)i * NBLK + blockIdx.x] = h[i];
}

// K2a: per-bucket column prefix over blocks (in place) -> totals.
// Thread i walks a CONTIGUOUS 2KB column (16 ints/line, L1-served).
__global__ void colprefix_kernel(int* __restrict__ partial,
                                 int* __restrict__ totals, int NB) {
    int i = blockIdx.x * blockDim.x + threadIdx.x;
    if (i >= 2 * NB) return;
    int* col = partial + (size_t)i * NBLK;
    int acc = 0;
    for (int b = 0; b < NBLK; ++b) {
        int t = col[b];
        col[b] = acc;          // exclusive per-block offset within bucket
        acc += t;
    }
    totals[i] = acc;
}

// K2b: exclusive scans of bucket totals -> bbD (dst stream), bbS (src stream).
__global__ void scan_kernel(const int* __restrict__ totals, int NB, int E, int N,
                            int* __restrict__ bbD, int* __restrict__ bbS,
                            int* __restrict__ row_ptr) {
    __shared__ int sc[MAXB];
    int tid = threadIdx.x;  // blockDim = MAXB
    int sumD = (tid < NB) ? totals[tid] : 0;
    sc[tid] = sumD;
    __syncthreads();
    for (int off = 1; off < MAXB; off <<= 1) {
        int v = (tid >= off) ? sc[tid - off] : 0;
        __syncthreads();
        sc[tid] += v;
        __syncthreads();
    }
    if (tid < NB) bbD[tid] = sc[tid] - sumD;
    if (tid == 0) { bbD[NB] = E; row_ptr[N] = E; }
    __syncthreads();
    int sumS = (tid < NB) ? totals[NB + tid] : 0;
    sc[tid] = sumS;
    __syncthreads();
    for (int off = 1; off < MAXB; off <<= 1) {
        int v = (tid >= off) ? sc[tid - off] : 0;
        __syncthreads();
        sc[tid] += v;
        __syncthreads();
    }
    if (tid < NB) bbS[tid] = sc[tid] - sumS;
    if (tid == 0) bbS[NB] = E;
}

// K3: single-pass scatter, ZERO global atomics. Block b's base for bucket i
// is bbX[i] + partial[i][b]; LDS counters dole out unique slots (totals match
// hist exactly: same grid-stride partition).
__global__ void scatter_kernel(const int* __restrict__ idx, int E, int NB,
                               const int* __restrict__ partial,
                               const int* __restrict__ bbD,
                               const int* __restrict__ bbS,
                               int* __restrict__ entry_pool,
                               int* __restrict__ key_pool) {
    __shared__ int cb[2 * MAXB];
    __shared__ int h[2 * MAXB];
    int tid = threadIdx.x;
    int b = blockIdx.x;
    for (int i = tid; i < 2 * NB; i += blockDim.x) {
        int base = (i < NB) ? bbD[i] : bbS[i - NB];
        cb[i] = base + partial[(size_t)i * NBLK + b];
        h[i] = 0;
    }
    __syncthreads();
    int stride = gridDim.x * blockDim.x;
    for (int e = b * blockDim.x + tid; e < E; e += stride) {
        int dst = idx[e], src = idx[E + e];
        int qd = dst >> 8;
        int sl = atomicAdd(&h[qd], 1);
        entry_pool[cb[qd] + sl] = (src << 8) | (dst & 255);  // src < 2^23 ok
        int qs = NB + (src >> 8);
        int sl2 = atomicAdd(&h[qs], 1);
        key_pool[cb[qs] + sl2] = src;
    }
}

// K4: per src-bucket count -> srcfac[n] = rsqrt(max(deg_src,1)).  512 thr.
__global__ void srccount_kernel(const int* __restrict__ key_pool,
                                const int* __restrict__ bbS,
                                float* __restrict__ srcfac, int N) {
    __shared__ int cnt[256];
    int q = blockIdx.x, tid = threadIdx.x;  // 512 threads
    if (tid < 256) cnt[tid] = 0;
    __syncthreads();
    int s0 = bbS[q], s1 = bbS[q + 1];
    for (int j = s0 + tid; j < s1; j += 512)
        atomicAdd(&cnt[key_pool[j] & 255], 1);
    __syncthreads();
    int node = q * 256 + tid;
    if (tid < 256 && node < N)
        srcfac[node] = rsqrtf(fmaxf((float)cnt[tid], 1.0f));
}

// K5: per dst-bucket: count, scan -> row_ptr; place src into CSR slots.
// csr writes confined to a 16KB L2-local region.  512 threads, guarded scan.
__global__ void order_kernel(const int* __restrict__ entry_pool,
                             const int* __restrict__ bbD,
                             int* __restrict__ row_ptr,
                             int* __restrict__ csr, int N) {
    __shared__ int cnt[256];
    __shared__ int pref[256];
    __shared__ int lcur[256];
    int q = blockIdx.x, tid = threadIdx.x;  // 512 threads
    if (tid < 256) cnt[tid] = 0;
    __syncthreads();
    int s0 = bbD[q], s1 = bbD[q + 1];
    for (int j = s0 + tid; j < s1; j += 512)
        atomicAdd(&cnt[entry_pool[j] & 255], 1);
    __syncthreads();
    int v = 0;
    if (tid < 256) { v = cnt[tid]; pref[tid] = v; }
    __syncthreads();
    for (int off = 1; off < 256; off <<= 1) {
        int u = (tid < 256 && tid >= off) ? pref[tid - off] : 0;
        __syncthreads();
        if (tid < 256) pref[tid] += u;
        __syncthreads();
    }
    if (tid < 256) {
        int excl = pref[tid] - v;
        int node = q * 256 + tid;
        if (node < N) row_ptr[node] = s0 + excl;
        lcur[tid] = 0;
        pref[tid] = excl;
    }
    __syncthreads();
    for (int j = s0 + tid; j < s1; j += 512) {
        int ent = entry_pool[j];
        int dl = ent & 255;
        int sl = atomicAdd(&lcur[dl], 1);
        csr[s0 + pref[dl] + sl] = ent >> 8;
    }
}

__device__ __forceinline__ unsigned short bfbits(float f) {
    __hip_bfloat16 h = __float2bfloat16(f);
    return *reinterpret_cast<unsigned short*>(&h);
}

// y'[n][d] = bf16( srcfac[n] * sum_k x[n][k] * W[d][k] )   (R4/R5-verified)
__global__ void proj_kernel(const float* __restrict__ x,
                            const float* __restrict__ W,
                            const float* __restrict__ srcfac,
                            unsigned short* __restrict__ y, int N) {
    __shared__ float Wt[64 * 68];
    int tid = threadIdx.x;
    for (int i = tid; i < 4096; i += 256) {
        int k = i & 63, dd = i >> 6;
        Wt[k * 68 + dd] = W[dd * 64 + k];
    }
    __syncthreads();

    int lane = tid & 63;
    int nl = lane >> 4;
    int g  = lane & 15;
    int wid = (blockIdx.x * blockDim.x + tid) >> 6;
    int nwaves = (gridDim.x * blockDim.x) >> 6;
    int ngrp = (N + 3) >> 2;

    for (int grp = wid; grp < ngrp; grp += nwaves) {
        int n = grp * 4 + nl;
        if (n >= N) continue;
        const float4* __restrict__ xr = (const float4*)(x + (long long)n * 64);
        float s = srcfac[n];
        float a0 = 0.f, a1 = 0.f, a2 = 0.f, a3 = 0.f;
#pragma unroll
        for (int kc = 0; kc < 16; ++kc) {
            float4 xv = xr[kc];
            const float* wp = &Wt[(kc * 4) * 68 + 4 * g];
            float4 w0 = *(const float4*)(wp);
            float4 w1 = *(const float4*)(wp + 68);
            float4 w2 = *(const float4*)(wp + 136);
            float4 w3 = *(const float4*)(wp + 204);
            a0 = fmaf(xv.x, w0.x, a0); a1 = fmaf(xv.x, w0.y, a1);
            a2 = fmaf(xv.x, w0.z, a2); a3 = fmaf(xv.x, w0.w, a3);
            a0 = fmaf(xv.y, w1.x, a0); a1 = fmaf(xv.y, w1.y, a1);
            a2 = fmaf(xv.y, w1.z, a2); a3 = fmaf(xv.y, w1.w, a3);
            a0 = fmaf(xv.z, w2.x, a0); a1 = fmaf(xv.z, w2.y, a1);
            a2 = fmaf(xv.z, w2.z, a2); a3 = fmaf(xv.z, w2.w, a3);
            a0 = fmaf(xv.w, w3.x, a0); a1 = fmaf(xv.w, w3.y, a1);
            a2 = fmaf(xv.w, w3.z, a2); a3 = fmaf(xv.w, w3.w, a3);
        }
        ushort4 pk;
        pk.x = bfbits(a0 * s); pk.y = bfbits(a1 * s);
        pk.z = bfbits(a2 * s); pk.w = bfbits(a3 * s);
        *(ushort4*)(y + (long long)n * 64 + 4 * g) = pk;
    }
}

// Wave per dst node: unweighted bf16 row sums, rsqrt(deg) scale + bias.
__global__ void spmm_kernel(const int* __restrict__ csr,
                            const int* __restrict__ row_ptr,
                            const unsigned short* __restrict__ y,
                            const float* __restrict__ b,
                            float* __restrict__ out, int N) {
    long long t = (long long)blockIdx.x * blockDim.x + threadIdx.x;
    int n = (int)(t >> 6);
    if (n >= N) return;
    int lane = (int)(t & 63);
    int eg = lane >> 3;
    int h  = lane & 7;

    int s0 = row_ptr[n];
    int cnt = row_ptr[n + 1] - s0;

    float acc[8];
#pragma unroll
    for (int j = 0; j < 8; ++j) acc[j] = 0.f;

    for (int i = 0; i < cnt; i += 16) {
        int e0 = i + eg, e1 = i + 8 + eg;
        float m0 = (e0 < cnt) ? 1.f : 0.f;
        float m1 = (e1 < cnt) ? 1.f : 0.f;
        int c0 = (e0 < cnt) ? csr[s0 + e0] : 0;
        int c1 = (e1 < cnt) ? csr[s0 + e1] : 0;
        uint4 r0 = ((const uint4*)(y + (long long)c0 * 64))[h];
        uint4 r1 = ((const uint4*)(y + (long long)c1 * 64))[h];
#pragma unroll
        for (int q = 0; q < 2; ++q) {
            uint4 r = q ? r1 : r0;
            float m = q ? m1 : m0;
            unsigned int ws4[4] = {r.x, r.y, r.z, r.w};
#pragma unroll
            for (int c = 0; c < 4; ++c) {
                float lo = __uint_as_float(ws4[c] << 16);
                float hi = __uint_as_float(ws4[c] & 0xffff0000u);
                acc[2 * c]     = fmaf(m, lo, acc[2 * c]);
                acc[2 * c + 1] = fmaf(m, hi, acc[2 * c + 1]);
            }
        }
    }
#pragma unroll
    for (int m = 8; m < 64; m <<= 1)
#pragma unroll
        for (int j = 0; j < 8; ++j) acc[j] += __shfl_xor(acc[j], m, 64);

    if (eg == 0) {
        float scl = rsqrtf(fmaxf((float)cnt, 1.0f));
        float4 b0 = ((const float4*)b)[h * 2];
        float4 b1 = ((const float4*)b)[h * 2 + 1];
        float4 o0 = {acc[0] * scl + b0.x, acc[1] * scl + b0.y,
                     acc[2] * scl + b0.z, acc[3] * scl + b0.w};
        float4 o1 = {acc[4] * scl + b1.x, acc[5] * scl + b1.y,
                     acc[6] * scl + b1.z, acc[7] * scl + b1.w};
        float4* op = (float4*)(out + (long long)n * 64);
        op[h * 2] = o0;
        op[h * 2 + 1] = o1;
    }
}

extern "C" void kernel_launch(void* const* d_in, const int* in_sizes, int n_in,
                              void* d_out, int out_size, void* d_ws, size_t ws_size,
                              hipStream_t stream) {
    const float* x  = (const float*)d_in[0];
    const int*  idx = (const int*)d_in[1];
    const float* W  = (const float*)d_in[2];
    const float* b  = (const float*)d_in[3];
    float*      out = (float*)d_out;

    const int N = in_sizes[0] / 64;
    const int E = in_sizes[1] / 2;
    const int NB = (N + 255) >> 8;   // 256-node buckets

    int* ws = (int*)d_ws;
    size_t o = 0;
    int* partial    = ws + o; o += (size_t)2 * NB * NBLK;
    int* totals     = ws + o; o += 2 * NB;
    int* bbD        = ws + o; o += NB + 1;
    int* bbS        = ws + o; o += NB + 1;
    int* row_ptr    = ws + o; o += N + 1;
    float* srcfac   = (float*)(ws + o); o += N;
    int* entry_pool = ws + o; o += E;
    int* key_pool   = ws + o; o += E;
    int* csr        = key_pool;      // alias: key_pool dead after srccount
    o = (o + 63) & ~(size_t)63;
    unsigned short* y = (unsigned short*)(ws + o);

    hist_kernel<<<NBLK, 256, 0, stream>>>(idx, E, NB, partial);

    colprefix_kernel<<<(2 * NB + 255) / 256, 256, 0, stream>>>(partial, totals, NB);

    scan_kernel<<<1, MAXB, 0, stream>>>(totals, NB, E, N, bbD, bbS, row_ptr);

    scatter_kernel<<<NBLK, 256, 0, stream>>>(idx, E, NB, partial, bbD, bbS,
                                             entry_pool, key_pool);

    srccount_kernel<<<NB, 512, 0, stream>>>(key_pool, bbS, srcfac, N);

    order_kernel<<<NB, 512, 0, stream>>>(entry_pool, bbD, row_ptr, csr, N);

    proj_kernel<<<1600, 256, 0, stream>>>(x, W, srcfac, y, N);

    spmm_kernel<<<(N * 64 + 255) / 256, 256, 0, stream>>>(csr, row_ptr, y, b,
                                                          out, N);
}